// Round 12
// baseline (29.450 us; speedup 1.0000x reference)
//
#include <hip/hip_runtime.h>

// B=16, N1=16, TOTAL_IN=1024 (two layers of 512 x dim 8), D1=64
// softmax rows sum to 1 =>  S[b,k,l] = sum_i (1 + rowsum_bias[k,i]) * U[b,k,i,l]
// v11: 2-chunk software pipeline per block (grid 512, 2 blocks/CU).
// While compute0 runs, the FULL chunk-1 load set (bias1+W1) is in flight:
// memory stays busy under compute, compute hides chunk-1 latency.
// All intra-block barriers are lgkm-only (never drain vmcnt).

#define LGKM_BARRIER()                                        \
    do {                                                      \
        asm volatile("s_waitcnt lgkmcnt(0)" ::: "memory");    \
        __builtin_amdgcn_s_barrier();                         \
        __builtin_amdgcn_sched_barrier(0);                    \
    } while (0)

__global__ __launch_bounds__(256) void proj_kernel(
        const float* __restrict__ x0, const float* __restrict__ x1,
        const float* __restrict__ W0, const float* __restrict__ W1,
        const float* __restrict__ bias, float* __restrict__ partial) {
    __shared__ float xs[2][16 * 132];   // per-chunk staged x, 528B row stride
    __shared__ float ssum[32];          // rows: [0..15] chunk0, [16..31] chunk1
    __shared__ float rbuf[4 * 8 * 64];  // [wave][bi][l] cross-wave reduction, 8KB
    const int tid = threadIdx.x;
    const int k  = blockIdx.x >> 5;        // [0,16)
    const int cp = blockIdx.x & 31;        // chunk pair [0,32)
    const int g  = tid >> 4;               // i_local [0,16)
    const int q  = tid & 15;               // l-quad  [0,16)
    const int w  = tid >> 6;               // wave    [0,4)
    const int gw = g & 3;                  // g within wave

    const int c0    = cp * 2;              // chunks c0, c0+1 (same layer always)
    const int layer = c0 >> 5;
    const int i0    = (c0 & 31) * 16;      // i of chunk0 within layer
    const int ig0   = c0 * 16;             // global i of chunk0
    const float* __restrict__ x = layer ? x1 : x0;
    const float* __restrict__ W = layer ? W1 : W0;

    // ---- 1. x loads for BOTH chunks (oldest)
    const float4* xpa = (const float4*)(x + (size_t)(g * 512 + i0 + q) * 8);
    float4 a0 = xpa[0], a1 = xpa[1];
    const float4* xpb = (const float4*)(x + (size_t)(g * 512 + i0 + 16 + q) * 8);
    float4 a2 = xpb[0], a3 = xpb[1];

    // ---- 2. bias chunk0 (row ig0+g), two 8-float4 batches
    const float4* bp0 = (const float4*)(bias + (size_t)(k * 1024 + ig0 + g) * 1024);
    float4 va[8], vb[8];
#pragma unroll
    for (int it = 0; it < 8; ++it) va[it] = bp0[q + 16 * it];
#pragma unroll
    for (int it = 0; it < 8; ++it) vb[it] = bp0[q + 16 * (8 + it)];

    // ---- 3. W chunk0: float4 idx of W[k][i0+g][j][q*4] = (k*512+i0+g)*128+j*16+q
    const float4* Wf4 = (const float4*)W;
    const size_t wb0 = (size_t)(k * 512 + i0 + g) * 128 + q;
    float4 wv0[8];
#pragma unroll
    for (int j = 0; j < 8; ++j) wv0[j] = Wf4[wb0 + j * 16];
    __builtin_amdgcn_sched_barrier(0);

    // ---- 4. bias0 rowsum -> ssum[g]  (waits x+bias0; W0 stays in flight)
    {
        float s0 = 0.f, s1 = 0.f, s2 = 0.f, s3 = 0.f;
#pragma unroll
        for (int it = 0; it < 8; it += 4) {
            s0 += va[it].x + va[it].y + va[it].z + va[it].w;
            s1 += va[it + 1].x + va[it + 1].y + va[it + 1].z + va[it + 1].w;
            s2 += va[it + 2].x + va[it + 2].y + va[it + 2].z + va[it + 2].w;
            s3 += va[it + 3].x + va[it + 3].y + va[it + 3].z + va[it + 3].w;
        }
#pragma unroll
        for (int it = 0; it < 8; it += 4) {
            s0 += vb[it].x + vb[it].y + vb[it].z + vb[it].w;
            s1 += vb[it + 1].x + vb[it + 1].y + vb[it + 1].z + vb[it + 1].w;
            s2 += vb[it + 2].x + vb[it + 2].y + vb[it + 2].z + vb[it + 2].w;
            s3 += vb[it + 3].x + vb[it + 3].y + vb[it + 3].z + vb[it + 3].w;
        }
        float s = (s0 + s1) + (s2 + s3);
#pragma unroll
        for (int m = 8; m >= 1; m >>= 1) s += __shfl_xor(s, m);  // 16-lane group
        if (q == 0) ssum[g] = 1.0f + s;
    }
    LGKM_BARRIER();

    // ---- 5. stage xs[0] = x(chunk0) * scale
    {
        const float s = ssum[q];
        *(float4*)&xs[0][q * 132 + g * 8] =
            make_float4(a0.x * s, a0.y * s, a0.z * s, a0.w * s);
        *(float4*)&xs[0][q * 132 + g * 8 + 4] =
            make_float4(a1.x * s, a1.y * s, a1.z * s, a1.w * s);
    }

    // ---- 6. prefetch chunk1: bias1 + W1 (fly across compute0)
    const float4* bp1 = bp0 + 4096;        // +16 rows (16*1024 floats)
    float4 u0[8], u1[8];
#pragma unroll
    for (int it = 0; it < 8; ++it) u0[it] = bp1[q + 16 * it];
#pragma unroll
    for (int it = 0; it < 8; ++it) u1[it] = bp1[q + 16 * (8 + it)];
    const size_t wb1 = wb0 + 16 * 128;     // +16 rows
    float4 wv1[8];
#pragma unroll
    for (int j = 0; j < 8; ++j) wv1[j] = Wf4[wb1 + j * 16];
    __builtin_amdgcn_sched_barrier(0);
    LGKM_BARRIER();                        // xs[0] visible; chunk1 loads in flight

    // ---- 7. compute chunk0 (wv0, xs[0]) -> partial tile (k*64+c0)
#pragma unroll
    for (int half = 0; half < 2; ++half) {
        float4 acc[8];
#pragma unroll
        for (int bi = 0; bi < 8; ++bi) acc[bi] = make_float4(0.f, 0.f, 0.f, 0.f);
#pragma unroll
        for (int bi = 0; bi < 8; ++bi) {
            const int b = half * 8 + bi;
            float xr[8];
            *(float4*)&xr[0] = *(const float4*)&xs[0][g * 132 + b * 8];
            *(float4*)&xr[4] = *(const float4*)&xs[0][g * 132 + b * 8 + 4];
#pragma unroll
            for (int j = 0; j < 8; ++j) {
                acc[bi].x += xr[j] * wv0[j].x;
                acc[bi].y += xr[j] * wv0[j].y;
                acc[bi].z += xr[j] * wv0[j].z;
                acc[bi].w += xr[j] * wv0[j].w;
            }
        }
#pragma unroll
        for (int bi = 0; bi < 8; ++bi) {
            acc[bi].x += __shfl_xor(acc[bi].x, 32); acc[bi].x += __shfl_xor(acc[bi].x, 16);
            acc[bi].y += __shfl_xor(acc[bi].y, 32); acc[bi].y += __shfl_xor(acc[bi].y, 16);
            acc[bi].z += __shfl_xor(acc[bi].z, 32); acc[bi].z += __shfl_xor(acc[bi].z, 16);
            acc[bi].w += __shfl_xor(acc[bi].w, 32); acc[bi].w += __shfl_xor(acc[bi].w, 16);
        }
        if (gw == 0) {
#pragma unroll
            for (int bi = 0; bi < 8; ++bi)
                *(float4*)&rbuf[(w * 8 + bi) * 64 + q * 4] = acc[bi];
        }
        LGKM_BARRIER();
        {
            const int bi = tid >> 5;
            const int l  = tid & 31;
            float v0 = 0.f, v1 = 0.f;
#pragma unroll
            for (int ww = 0; ww < 4; ++ww) {
                v0 += rbuf[(ww * 8 + bi) * 64 + l];
                v1 += rbuf[(ww * 8 + bi) * 64 + l + 32];
            }
            const int b = half * 8 + bi;
            partial[((size_t)(k * 64 + c0)) * 1024 + b * 64 + l]      = v0;
            partial[((size_t)(k * 64 + c0)) * 1024 + b * 64 + l + 32] = v1;
        }
        LGKM_BARRIER();
    }

    // ---- 8. bias1 rowsum -> ssum[16+g]
    {
        float s0 = 0.f, s1 = 0.f, s2 = 0.f, s3 = 0.f;
#pragma unroll
        for (int it = 0; it < 8; it += 4) {
            s0 += u0[it].x + u0[it].y + u0[it].z + u0[it].w;
            s1 += u0[it + 1].x + u0[it + 1].y + u0[it + 1].z + u0[it + 1].w;
            s2 += u0[it + 2].x + u0[it + 2].y + u0[it + 2].z + u0[it + 2].w;
            s3 += u0[it + 3].x + u0[it + 3].y + u0[it + 3].z + u0[it + 3].w;
        }
#pragma unroll
        for (int it = 0; it < 8; it += 4) {
            s0 += u1[it].x + u1[it].y + u1[it].z + u1[it].w;
            s1 += u1[it + 1].x + u1[it + 1].y + u1[it + 1].z + u1[it + 1].w;
            s2 += u1[it + 2].x + u1[it + 2].y + u1[it + 2].z + u1[it + 2].w;
            s3 += u1[it + 3].x + u1[it + 3].y + u1[it + 3].z + u1[it + 3].w;
        }
        float s = (s0 + s1) + (s2 + s3);
#pragma unroll
        for (int m = 8; m >= 1; m >>= 1) s += __shfl_xor(s, m);
        if (q == 0) ssum[16 + g] = 1.0f + s;
    }
    LGKM_BARRIER();

    // ---- 9. stage xs[1] = x(chunk1) * scale
    {
        const float s = ssum[16 + q];
        *(float4*)&xs[1][q * 132 + g * 8] =
            make_float4(a2.x * s, a2.y * s, a2.z * s, a2.w * s);
        *(float4*)&xs[1][q * 132 + g * 8 + 4] =
            make_float4(a3.x * s, a3.y * s, a3.z * s, a3.w * s);
    }
    LGKM_BARRIER();

    // ---- 10. compute chunk1 (wv1, xs[1]) -> partial tile (k*64+c0+1)
#pragma unroll
    for (int half = 0; half < 2; ++half) {
        float4 acc[8];
#pragma unroll
        for (int bi = 0; bi < 8; ++bi) acc[bi] = make_float4(0.f, 0.f, 0.f, 0.f);
#pragma unroll
        for (int bi = 0; bi < 8; ++bi) {
            const int b = half * 8 + bi;
            float xr[8];
            *(float4*)&xr[0] = *(const float4*)&xs[1][g * 132 + b * 8];
            *(float4*)&xr[4] = *(const float4*)&xs[1][g * 132 + b * 8 + 4];
#pragma unroll
            for (int j = 0; j < 8; ++j) {
                acc[bi].x += xr[j] * wv1[j].x;
                acc[bi].y += xr[j] * wv1[j].y;
                acc[bi].z += xr[j] * wv1[j].z;
                acc[bi].w += xr[j] * wv1[j].w;
            }
        }
#pragma unroll
        for (int bi = 0; bi < 8; ++bi) {
            acc[bi].x += __shfl_xor(acc[bi].x, 32); acc[bi].x += __shfl_xor(acc[bi].x, 16);
            acc[bi].y += __shfl_xor(acc[bi].y, 32); acc[bi].y += __shfl_xor(acc[bi].y, 16);
            acc[bi].z += __shfl_xor(acc[bi].z, 32); acc[bi].z += __shfl_xor(acc[bi].z, 16);
            acc[bi].w += __shfl_xor(acc[bi].w, 32); acc[bi].w += __shfl_xor(acc[bi].w, 16);
        }
        if (gw == 0) {
#pragma unroll
            for (int bi = 0; bi < 8; ++bi)
                *(float4*)&rbuf[(w * 8 + bi) * 64 + q * 4] = acc[bi];
        }
        LGKM_BARRIER();
        {
            const int bi = tid >> 5;
            const int l  = tid & 31;
            float v0 = 0.f, v1 = 0.f;
#pragma unroll
            for (int ww = 0; ww < 4; ++ww) {
                v0 += rbuf[(ww * 8 + bi) * 64 + l];
                v1 += rbuf[(ww * 8 + bi) * 64 + l + 32];
            }
            const int b = half * 8 + bi;
            partial[((size_t)(k * 64 + c0 + 1)) * 1024 + b * 64 + l]      = v0;
            partial[((size_t)(k * 64 + c0 + 1)) * 1024 + b * 64 + l + 32] = v1;
        }
        LGKM_BARRIER();
    }
}

// ---------------------------------------------------------------------------
// One block per (b,k) row: S[b,k,l] = sum over 64 chunk partials; squash.
__global__ __launch_bounds__(256) void reduce_squash_kernel(
        const float* __restrict__ partial, float* __restrict__ out) {
    __shared__ float red[4][64];
    const int row = blockIdx.x;            // [0,256) = b*16 + k
    const int b = row >> 4, k = row & 15;
    const int w = threadIdx.x >> 6, lane = threadIdx.x & 63;
    float s = 0.f;
#pragma unroll
    for (int cc = 0; cc < 16; ++cc) {
        const int c = w + cc * 4;          // wave-interleaved chunks [0,64)
        s += partial[((size_t)(k * 64 + c)) * 1024 + b * 64 + lane];
    }
    red[w][lane] = s;
    __syncthreads();
    if (w == 0) {
        float v = red[0][lane] + red[1][lane] + red[2][lane] + red[3][lane];
        float sq = v * v;
#pragma unroll
        for (int m = 32; m >= 1; m >>= 1) sq += __shfl_xor(sq, m);
        out[(size_t)row * 64 + lane] = (sq / (1.0f + sq)) * v / (sqrtf(sq) + 1e-5f);
    }
}

// ---------------------------------------------------------------------------
extern "C" void kernel_launch(void* const* d_in, const int* in_sizes, int n_in,
                              void* d_out, int out_size, void* d_ws, size_t ws_size,
                              hipStream_t stream) {
    const float* x0  = (const float*)d_in[0];   // [16,512,8]
    const float* x1  = (const float*)d_in[1];   // [16,512,8]
    const float* W0  = (const float*)d_in[2];   // [16,512,8,64]
    const float* W1  = (const float*)d_in[3];   // [16,512,8,64]
    const float* bia = (const float*)d_in[4];   // [16,1024,1024]
    float* out = (float*)d_out;                 // [16,16,64]

    float* partial = (float*)d_ws;              // 1024*1024 floats = 4 MB

    proj_kernel<<<dim3(512), dim3(256), 0, stream>>>(x0, x1, W0, W1, bia, partial);
    reduce_squash_kernel<<<dim3(256), dim3(256), 0, stream>>>(partial, out);
}